// Round 6
// baseline (138.588 us; speedup 1.0000x reference)
//
#include <hip/hip_runtime.h>

// SobelLoss: mean over 3 dirs of mean |sobel(moved) - sobel(label)|.
// conv(m)-conv(l) = conv(m-l); separable: s=[1,2,1], d=[-1,0,1]:
//   gx = sH(dW) rolled sD;  gy = dH(sW) rolled sD;  gz = sH(sW) rolled -dD.
// R6: BARRIERLESS. R5's counters (hbm 16%, VALU 20%, occ 17%) showed the
// staged-LDS loop is serialized by the per-plane __syncthreads vmcnt(0)
// drain. New structure: lanes = W (coalesced), H rows in registers (4 out,
// 6 in per thread), D rolling window in registers, W-halo via shifted
// loads (L1-resident lines). No LDS staging, no barriers in the hot loop;
// latency hidden purely by 18 waves/CU of TLP.
// HARD-WON RULES (R2/R4): no __launch_bounds__ min-waves clamp (spills the
// rolling window -> 200-480 MB scratch traffic).

#define BB 2
#define DD 160
#define HH 192
#define WW 160
#define HW (HH * WW)

#define TH 4                    // output H rows per thread
#define DC 10                   // output D planes per wave
#define NTHREADS 256            // 4 waves; each wave = own H-tile

__global__ __launch_bounds__(NTHREADS) void sobel_loss_kernel(
    const float* __restrict__ moved, const float* __restrict__ label,
    float* __restrict__ out)
{
    __shared__ float red[NTHREADS / 64];

    const int tid   = threadIdx.x;
    const int lane  = tid & 63;
    const int wavei = tid >> 6;                 // 0..3
    const int wch   = blockIdx.x % 3;           // W chunk: 0,1,2
    const int hgrp  = blockIdx.x / 3;           // 0..11
    const int htile = hgrp * 4 + wavei;         // 0..47
    const int hbase = htile * TH;               // 0..188
    const int d0    = blockIdx.y * DC;          // 16 chunks
    const int b     = blockIdx.z;               // 2
    const int base_b = b * (DD * HW);

    const int  w     = wch * 64 + lane;         // 0..191 (>=160 inactive)
    const bool wact  = w < WW;
    const bool hasl  = wact && (w > 0);
    const bool hasr  = (w + 1) < WW;
    const int  wc    = min(w, WW - 1);
    const int  wl    = max(w - 1, 0);
    const int  wr    = min(w + 1, WW - 1);

    float px1[TH], px2[TH], py1[TH], py2[TH], pz1[TH], pz2[TH];
#pragma unroll
    for (int i = 0; i < TH; ++i) {
        px1[i] = px2[i] = 0.f;
        py1[i] = py2[i] = 0.f;
        pz1[i] = pz2[i] = 0.f;
    }
    float acc = 0.f;

    for (int it = 0; it < DC + 2; ++it) {
        const int  p  = d0 - 1 + it;
        const bool pv = (unsigned)p < (unsigned)DD;   // block-uniform

        float sW[TH + 2], dW[TH + 2];
        if (pv) {
            const int pbase = base_b + p * HW;
#pragma unroll
            for (int r = 0; r < TH + 2; ++r) {
                const int  gh  = hbase - 1 + r;
                const bool rv  = (unsigned)gh < (unsigned)HH;
                const int  ghc = min(max(gh, 0), HH - 1);
                const float* mrow = moved + pbase + ghc * WW;
                const float* lrow = label + pbase + ghc * WW;
                const float mcv = mrow[wc], mlv = mrow[wl], mrv = mrow[wr];
                const float lcv = lrow[wc], llv = lrow[wl], lrv = lrow[wr];
                const bool vc = rv && wact;
                const float d_c = vc           ? mcv - lcv : 0.f;
                const float d_l = (rv && hasl) ? mlv - llv : 0.f;
                const float d_r = (rv && hasr) ? mrv - lrv : 0.f;
                sW[r] = (d_l + d_r) + 2.f * d_c;   // W-smooth of diff
                dW[r] = d_r - d_l;                 // W-deriv  of diff
            }
        } else {
#pragma unroll
            for (int r = 0; r < TH + 2; ++r) { sW[r] = 0.f; dW[r] = 0.f; }
        }

#pragma unroll
        for (int i = 0; i < TH; ++i) {
            const float px = (dW[i] + dW[i + 2]) + 2.f * dW[i + 1];  // sH(dW)
            const float pz = (sW[i] + sW[i + 2]) + 2.f * sW[i + 1];  // sH(sW)
            const float py = sW[i + 2] - sW[i];                      // dH(sW)
            if (it >= 2) {   // output plane q = p-1 = d0+it-2 in [d0, d0+DC)
                const float gx = px2[i] + 2.f * px1[i] + px;   // sD
                const float gy = py2[i] + 2.f * py1[i] + py;   // sD
                const float gz = pz2[i] - pz;                  // dD: (q-1)-(q+1)
                acc += fabsf(gx) + fabsf(gy) + fabsf(gz);
            }
            px2[i] = px1[i]; px1[i] = px;
            py2[i] = py1[i]; py1[i] = py;
            pz2[i] = pz1[i]; pz1[i] = pz;
        }
    }

    // ---- reduce: wave shuffle -> LDS -> one atomic per block ----
#pragma unroll
    for (int off = 32; off > 0; off >>= 1)
        acc += __shfl_down(acc, off, 64);
    if (lane == 0) red[wavei] = acc;
    __syncthreads();
    if (tid == 0) {
        const float s = red[0] + red[1] + red[2] + red[3];
        atomicAdd(out, s * (1.0f / (3.0f * BB * DD * HH * WW)));
    }
}

extern "C" void kernel_launch(void* const* d_in, const int* in_sizes, int n_in,
                              void* d_out, int out_size, void* d_ws, size_t ws_size,
                              hipStream_t stream) {
    const float* moved = (const float*)d_in[0];
    const float* label = (const float*)d_in[1];
    float* out = (float*)d_out;
    (void)in_sizes; (void)n_in; (void)out_size; (void)d_ws; (void)ws_size;

    hipMemsetAsync(out, 0, sizeof(float), stream);
    // x: 3 W-chunks * 12 H-groups; y: 16 D-chunks; z: batch
    dim3 grid(36, DD / DC, BB);     // 1152 blocks = 4608 waves (~18/CU)
    sobel_loss_kernel<<<grid, NTHREADS, 0, stream>>>(moved, label, out);
}

// Round 7
// 117.302 us; speedup vs baseline: 1.1815x; 1.1815x over previous
//
#include <hip/hip_runtime.h>

// SobelLoss: mean over 3 dirs of mean |sobel(moved) - sobel(label)|.
// conv(m)-conv(l) = conv(m-l); separable: s=[1,2,1], d=[-1,0,1]:
//   gx = sH(dW) rolled sD;  gy = dH(sW) rolled sD;  gz = sH(sW) rolled -dD.
// R7: barrierless register pipeline. R6 showed the compiler (VGPR=40!)
// serialized 36 loads/iter into small waitcnt groups -> exposed latency.
// Fix: 12 loads/iter (1 per row per array; W-neighbors via __shfl of the
// diff), explicit double-buffered next-plane prefetch, full unroll so
// rolling windows and plane buffers are register-renamed. No LDS staging,
// no __syncthreads in the hot loop.
// HARD-WON RULES (R2/R4): no __launch_bounds__ min-waves clamp (spills
// the rolling window -> 200-480 MB scratch traffic). DMA predicates must
// be wave-uniform (moot here: no DMA).

#define BB 2
#define DD 160
#define HH 192
#define WW 160
#define HW (HH * WW)

#define TH 4                    // output H rows per thread
#define DC 8                    // output D planes per wave
#define NIT (DC + 2)            // 10
#define NTHREADS 256            // 4 waves; each wave = own H-tile

__global__ __launch_bounds__(NTHREADS) void sobel_loss_kernel(
    const float* __restrict__ moved, const float* __restrict__ label,
    float* __restrict__ out)
{
    __shared__ float red[NTHREADS / 64];

    const int tid   = threadIdx.x;
    const int lane  = tid & 63;
    const int wavei = tid >> 6;                 // 0..3
    const int wch   = blockIdx.x % 3;           // W chunk: 62 outputs each
    const int hgrp  = blockIdx.x / 3;           // 0..11
    const int hbase = (hgrp * 4 + wavei) * TH;  // 0..188
    const int d0    = blockIdx.y * DC;          // 20 chunks
    const int base_b = blockIdx.z * (DD * HW);

    // lane l holds column w = w0 + l - 1; outputs live on lanes 1..62
    const int  w0 = wch * 62;                   // 0, 62, 124
    const int  w  = w0 + lane - 1;              // -1 .. 186
    const bool wv = (unsigned)w < (unsigned)WW;
    const int  gw = min(max(w, 0), WW - 1);
    const bool outv = (lane >= 1) && (lane <= 62) && (w < WW);

    // per-row constants (fixed per thread across all D iterations)
    int  rowOff[TH + 2];
    bool rv[TH + 2];
#pragma unroll
    for (int r = 0; r < TH + 2; ++r) {
        const int gh = hbase - 1 + r;
        rv[r] = (unsigned)gh < (unsigned)HH;
        rowOff[r] = min(max(gh, 0), HH - 1) * WW + gw;
    }

    float mc[TH + 2], lc[TH + 2], mn[TH + 2], ln[TH + 2];
    {   // preload plane d0-1 (clamped; masked by pv at compute)
        const int pb = base_b + max(d0 - 1, 0) * HW;
#pragma unroll
        for (int r = 0; r < TH + 2; ++r) {
            mc[r] = moved[pb + rowOff[r]];
            lc[r] = label[pb + rowOff[r]];
        }
    }

    float px1[TH], px2[TH], py1[TH], py2[TH], pz1[TH], pz2[TH];
#pragma unroll
    for (int i = 0; i < TH; ++i) {
        px1[i] = px2[i] = 0.f;
        py1[i] = py2[i] = 0.f;
        pz1[i] = pz2[i] = 0.f;
    }
    float acc = 0.f;

#pragma unroll
    for (int it = 0; it < NIT; ++it) {
        // ---- issue next plane's 12 loads; consumed next iteration ----
        if (it + 1 < NIT) {
            const int pb = base_b + min(d0 + it, DD - 1) * HW;
#pragma unroll
            for (int r = 0; r < TH + 2; ++r) {
                mn[r] = moved[pb + rowOff[r]];
                ln[r] = label[pb + rowOff[r]];
            }
        }

        // ---- compute on current plane ----
        const bool pv = (unsigned)(d0 - 1 + it) < (unsigned)DD;
        float sW[TH + 2], dW[TH + 2];
#pragma unroll
        for (int r = 0; r < TH + 2; ++r) {
            const float d  = (pv && rv[r] && wv) ? (mc[r] - lc[r]) : 0.f;
            const float dl = __shfl_up(d, 1, 64);    // w-1 (lane 0 junk, masked)
            const float dr = __shfl_down(d, 1, 64);  // w+1 (lane 63 junk, masked)
            sW[r] = (dl + dr) + 2.f * d;   // W-smooth
            dW[r] = dr - dl;               // W-deriv
        }
#pragma unroll
        for (int i = 0; i < TH; ++i) {
            const float px = (dW[i] + dW[i + 2]) + 2.f * dW[i + 1];  // sH(dW)
            const float pz = (sW[i] + sW[i + 2]) + 2.f * sW[i + 1];  // sH(sW)
            const float py = sW[i + 2] - sW[i];                      // dH(sW)
            if (it >= 2 && outv) {
                const float gx = px2[i] + 2.f * px1[i] + px;   // sD
                const float gy = py2[i] + 2.f * py1[i] + py;   // sD
                const float gz = pz2[i] - pz;                  // dD: (q-1)-(q+1)
                acc += fabsf(gx) + fabsf(gy) + fabsf(gz);
            }
            px2[i] = px1[i]; px1[i] = px;
            py2[i] = py1[i]; py1[i] = py;
            pz2[i] = pz1[i]; pz1[i] = pz;
        }

        // ---- rotate plane buffers (renamed away by the unroll) ----
#pragma unroll
        for (int r = 0; r < TH + 2; ++r) { mc[r] = mn[r]; lc[r] = ln[r]; }
    }

    // ---- reduce: wave shuffle -> LDS -> one atomic per block ----
#pragma unroll
    for (int off = 32; off > 0; off >>= 1)
        acc += __shfl_down(acc, off, 64);
    if (lane == 0) red[wavei] = acc;
    __syncthreads();
    if (tid == 0) {
        const float s = red[0] + red[1] + red[2] + red[3];
        atomicAdd(out, s * (1.0f / (3.0f * BB * DD * HH * WW)));
    }
}

extern "C" void kernel_launch(void* const* d_in, const int* in_sizes, int n_in,
                              void* d_out, int out_size, void* d_ws, size_t ws_size,
                              hipStream_t stream) {
    const float* moved = (const float*)d_in[0];
    const float* label = (const float*)d_in[1];
    float* out = (float*)d_out;
    (void)in_sizes; (void)n_in; (void)out_size; (void)d_ws; (void)ws_size;

    hipMemsetAsync(out, 0, sizeof(float), stream);
    // x: 3 W-chunks * 12 H-groups; y: 20 D-chunks; z: batch
    dim3 grid(36, DD / DC, BB);     // 1440 blocks = 5760 waves (~22.5/CU)
    sobel_loss_kernel<<<grid, NTHREADS, 0, stream>>>(moved, label, out);
}